// Round 4
// baseline (31.430 us; speedup 1.0000x reference)
//
#include <hip/hip_runtime.h>

// MultiLevelEmbedding: out[b,t,:] = emb_tables[level_ids[b,t], token_ids[b,t], :]
//                                 + level_embed[level_ids[b,t], :]
// B=64, T=1024, L=4, VOCAB=258, D=512, fp32.
// HBM-write-bound: 128 MiB out-stream; gather sources are L2/L1-resident.
//
// Round-4 structure:
//  - wave w owns 8 CONSECUTIVE rows [8w, 8w+8): its 16 index loads merge into
//    a few s_load_dwordx8 at wave start (scalar latency paid once, off the
//    per-iteration critical path), and its stores stream 16 KiB contiguously.
//  - REGULAR stores (not nontemporal): the harness fill calibrates the regular
//    store path at 6.8-7.0 TB/s; nt was the prior kernel's unproven variable.
//  - 2 rows in flight per step (independent gather chains), full row in two
//    coalesced 1 KiB accesses (lane l -> f4 elems l and l+64).

#define MLE_D     512
#define MLE_D4    128   // float4 per row
#define MLE_VOCAB 258
#define ROWS_PER_WAVE 8

typedef float f32x4 __attribute__((ext_vector_type(4)));

__global__ __launch_bounds__(256, 4) void MultiLevelEmbedding_34437047780006_kernel(
    const int* __restrict__ level_ids,
    const int* __restrict__ token_ids,
    const float* __restrict__ emb_tables,
    const float* __restrict__ level_embed,
    float* __restrict__ out,
    int nrows)
{
    const int lane = (int)(threadIdx.x & 63);
    const int wib  = __builtin_amdgcn_readfirstlane((int)(threadIdx.x >> 6));
    const int gw   = (int)blockIdx.x * 4 + wib;          // global wave id (uniform)
    const int base = gw * ROWS_PER_WAVE;
    if (base >= nrows) return;

    const f32x4* __restrict__ levv = reinterpret_cast<const f32x4*>(level_embed);

    if (base + ROWS_PER_WAVE <= nrows) {
        // ---- fast path: full 8-row slab ----
        // All 16 index loads up front; base is wave-uniform so these become
        // merged scalar loads (s_load_dwordx8).
        int lvl[ROWS_PER_WAVE], tok[ROWS_PER_WAVE];
#pragma unroll
        for (int k = 0; k < ROWS_PER_WAVE; ++k) {
            lvl[k] = level_ids[base + k];
            tok[k] = token_ids[base + k];
        }

        for (int k = 0; k < ROWS_PER_WAVE; k += 2) {
            const f32x4* __restrict__ t0 = reinterpret_cast<const f32x4*>(
                emb_tables + (long long)(lvl[k]     * MLE_VOCAB + tok[k])     * MLE_D);
            const f32x4* __restrict__ t1 = reinterpret_cast<const f32x4*>(
                emb_tables + (long long)(lvl[k + 1] * MLE_VOCAB + tok[k + 1]) * MLE_D);

            f32x4 a0 = t0[lane];
            f32x4 b0 = t0[lane + 64];
            f32x4 a1 = t1[lane];
            f32x4 b1 = t1[lane + 64];

            f32x4 la0 = levv[lvl[k]     * MLE_D4 + lane];
            f32x4 lb0 = levv[lvl[k]     * MLE_D4 + lane + 64];
            f32x4 la1 = levv[lvl[k + 1] * MLE_D4 + lane];
            f32x4 lb1 = levv[lvl[k + 1] * MLE_D4 + lane + 64];

            f32x4* __restrict__ o0 = reinterpret_cast<f32x4*>(out + (long long)(base + k)     * MLE_D);
            f32x4* __restrict__ o1 = reinterpret_cast<f32x4*>(out + (long long)(base + k + 1) * MLE_D);

            o0[lane]      = a0 + la0;
            o0[lane + 64] = b0 + lb0;
            o1[lane]      = a1 + la1;
            o1[lane + 64] = b1 + lb1;
        }
    } else {
        // ---- tail: per-row ----
        for (int r = base; r < nrows; ++r) {
            const int lvl = __builtin_amdgcn_readfirstlane(level_ids[r]);
            const int tok = __builtin_amdgcn_readfirstlane(token_ids[r]);
            const f32x4* __restrict__ t = reinterpret_cast<const f32x4*>(
                emb_tables + (long long)(lvl * MLE_VOCAB + tok) * MLE_D);
            f32x4 a = t[lane];
            f32x4 b = t[lane + 64];
            f32x4 la = levv[lvl * MLE_D4 + lane];
            f32x4 lb = levv[lvl * MLE_D4 + lane + 64];
            f32x4* __restrict__ o = reinterpret_cast<f32x4*>(out + (long long)r * MLE_D);
            o[lane]      = a + la;
            o[lane + 64] = b + lb;
        }
    }
}

extern "C" void kernel_launch(void* const* d_in, const int* in_sizes, int n_in,
                              void* d_out, int out_size, void* d_ws, size_t ws_size,
                              hipStream_t stream) {
    const int*   level_ids   = (const int*)d_in[0];
    const int*   token_ids   = (const int*)d_in[1];
    const float* emb_tables  = (const float*)d_in[2];
    const float* level_embed = (const float*)d_in[3];
    float*       out         = (float*)d_out;

    const int nrows = in_sizes[0];   // B*T = 65536

    const int block = 256;                                     // 4 waves/block
    const int rows_per_block = 4 * ROWS_PER_WAVE;              // 32
    int grid = (nrows + rows_per_block - 1) / rows_per_block;  // 2048 at B*T=65536

    MultiLevelEmbedding_34437047780006_kernel<<<grid, block, 0, stream>>>(
        level_ids, token_ids, emb_tables, level_embed, out, nrows);
}

// Round 5
// 28.519 us; speedup vs baseline: 1.1021x; 1.1021x over previous
//
#include <hip/hip_runtime.h>

// MultiLevelEmbedding: out[b,t,:] = emb_tables[level_ids[b,t], token_ids[b,t], :]
//                                 + level_embed[level_ids[b,t], :]
// B=64, T=1024, L=4, VOCAB=258, D=512, fp32.
// HBM-write-bound: 128 MiB out-stream; tables (2 MiB) are L2-resident.
//
// Round-5 = round-3 (27.4 us: nt stores + strided wave<->row + scalar idx)
// with ONE change: all 16 index loads hoisted to wave start, fully unrolled
// (registers, no runtime-indexed arrays). Round 3 paid 4 dependent scalar
// load latencies per iteration; now they all fly concurrently, once.
//
//  - wave w owns rows {w + j*nw}, j=0..7 (strided; at any instant the write
//    window across waves is a dense moving 16 MiB band).
//  - nontemporal stores: keep the 128 MiB write stream from evicting the
//    tables out of per-XCD L2 (round 4 showed regular stores cost ~4 us).
//  - lane l covers f4 elems l and l+64 -> two coalesced 1 KiB accesses/row.

#define MLE_D     512
#define MLE_D4    128   // float4 per row
#define MLE_VOCAB 258
#define RPW       8     // rows per wave

typedef float f32x4 __attribute__((ext_vector_type(4)));

__global__ __launch_bounds__(256) void MultiLevelEmbedding_34437047780006_kernel(
    const int* __restrict__ level_ids,
    const int* __restrict__ token_ids,
    const float* __restrict__ emb_tables,
    const float* __restrict__ level_embed,
    float* __restrict__ out,
    int nrows)
{
    const int lane = (int)(threadIdx.x & 63);
    const int wib  = __builtin_amdgcn_readfirstlane((int)(threadIdx.x >> 6));
    const int nw   = (int)gridDim.x * 4;       // total waves
    const int gw   = (int)blockIdx.x * 4 + wib; // this wave's id (SGPR)

    const f32x4* __restrict__ levv = reinterpret_cast<const f32x4*>(level_embed);

    if (gw + (RPW - 1) * nw < nrows) {
        // ---- fast path: exactly RPW strided rows ----
        // Hoist all index loads; fully unrolled -> pure registers (SGPRs).
        int lvl0, lvl1, lvl2, lvl3, lvl4, lvl5, lvl6, lvl7;
        int tok0, tok1, tok2, tok3, tok4, tok5, tok6, tok7;
        lvl0 = __builtin_amdgcn_readfirstlane(level_ids[gw + 0 * nw]);
        lvl1 = __builtin_amdgcn_readfirstlane(level_ids[gw + 1 * nw]);
        lvl2 = __builtin_amdgcn_readfirstlane(level_ids[gw + 2 * nw]);
        lvl3 = __builtin_amdgcn_readfirstlane(level_ids[gw + 3 * nw]);
        lvl4 = __builtin_amdgcn_readfirstlane(level_ids[gw + 4 * nw]);
        lvl5 = __builtin_amdgcn_readfirstlane(level_ids[gw + 5 * nw]);
        lvl6 = __builtin_amdgcn_readfirstlane(level_ids[gw + 6 * nw]);
        lvl7 = __builtin_amdgcn_readfirstlane(level_ids[gw + 7 * nw]);
        tok0 = __builtin_amdgcn_readfirstlane(token_ids[gw + 0 * nw]);
        tok1 = __builtin_amdgcn_readfirstlane(token_ids[gw + 1 * nw]);
        tok2 = __builtin_amdgcn_readfirstlane(token_ids[gw + 2 * nw]);
        tok3 = __builtin_amdgcn_readfirstlane(token_ids[gw + 3 * nw]);
        tok4 = __builtin_amdgcn_readfirstlane(token_ids[gw + 4 * nw]);
        tok5 = __builtin_amdgcn_readfirstlane(token_ids[gw + 5 * nw]);
        tok6 = __builtin_amdgcn_readfirstlane(token_ids[gw + 6 * nw]);
        tok7 = __builtin_amdgcn_readfirstlane(token_ids[gw + 7 * nw]);

#define MLE_ROW(J, LVL, TOK)                                                      \
        {                                                                         \
            const f32x4* __restrict__ t = reinterpret_cast<const f32x4*>(         \
                emb_tables + (long long)((LVL) * MLE_VOCAB + (TOK)) * MLE_D);     \
            f32x4 a = t[lane];                                                    \
            f32x4 b = t[lane + 64];                                               \
            f32x4 la = levv[(LVL) * MLE_D4 + lane];                               \
            f32x4 lb = levv[(LVL) * MLE_D4 + lane + 64];                          \
            f32x4* __restrict__ o = reinterpret_cast<f32x4*>(                     \
                out + (long long)(gw + (J) * nw) * MLE_D);                        \
            __builtin_nontemporal_store(a + la, o + lane);                        \
            __builtin_nontemporal_store(b + lb, o + lane + 64);                   \
        }

        MLE_ROW(0, lvl0, tok0)
        MLE_ROW(1, lvl1, tok1)
        MLE_ROW(2, lvl2, tok2)
        MLE_ROW(3, lvl3, tok3)
        MLE_ROW(4, lvl4, tok4)
        MLE_ROW(5, lvl5, tok5)
        MLE_ROW(6, lvl6, tok6)
        MLE_ROW(7, lvl7, tok7)
#undef MLE_ROW
    } else {
        // ---- tail: per-row strided loop ----
        for (int r = gw; r < nrows; r += nw) {
            const int lvl = __builtin_amdgcn_readfirstlane(level_ids[r]);
            const int tok = __builtin_amdgcn_readfirstlane(token_ids[r]);
            const f32x4* __restrict__ t = reinterpret_cast<const f32x4*>(
                emb_tables + (long long)(lvl * MLE_VOCAB + tok) * MLE_D);
            f32x4 a = t[lane];
            f32x4 b = t[lane + 64];
            f32x4 la = levv[lvl * MLE_D4 + lane];
            f32x4 lb = levv[lvl * MLE_D4 + lane + 64];
            f32x4* __restrict__ o = reinterpret_cast<f32x4*>(out + (long long)r * MLE_D);
            __builtin_nontemporal_store(a + la, o + lane);
            __builtin_nontemporal_store(b + lb, o + lane + 64);
        }
    }
}

extern "C" void kernel_launch(void* const* d_in, const int* in_sizes, int n_in,
                              void* d_out, int out_size, void* d_ws, size_t ws_size,
                              hipStream_t stream) {
    const int*   level_ids   = (const int*)d_in[0];
    const int*   token_ids   = (const int*)d_in[1];
    const float* emb_tables  = (const float*)d_in[2];
    const float* level_embed = (const float*)d_in[3];
    float*       out         = (float*)d_out;

    const int nrows = in_sizes[0];   // B*T = 65536

    const int block = 256;                              // 4 waves/block
    const int rows_per_block = 4 * RPW;                 // 32
    int grid = (nrows + rows_per_block - 1) / rows_per_block;  // 2048

    MultiLevelEmbedding_34437047780006_kernel<<<grid, block, 0, stream>>>(
        level_ids, token_ids, emb_tables, level_embed, out, nrows);
}